// Round 2
// baseline (2268.972 us; speedup 1.0000x reference)
//
#include <hip/hip_runtime.h>
#include <hip/hip_bf16.h>

// Problem constants
#define NQ   8192      // B*H*W = 8*32*32 queries
#define NK   16384     // codebook entries
#define DIM  2048      // embedding dim
#define KTILES 128     // NK / 128
#define QUANT_ELEMS (8*2048*32*32)  // 16777216

typedef __attribute__((ext_vector_type(8))) short bf16x8;
typedef __attribute__((ext_vector_type(4))) float f32x4;

// ---------------- async global->LDS 16B copy (wave-uniform LDS base) -------
__device__ __forceinline__ void async16(const void* g, void* lds) {
  __builtin_amdgcn_global_load_lds(
      (const __attribute__((address_space(1))) unsigned int*)g,
      (__attribute__((address_space(3))) unsigned int*)lds,
      16, 0, 0);
}

// ---------------- top-2 helper --------------------------------------------
__device__ __forceinline__ void t2_add(float v, int i,
                                       float& v1, int& i1, float& v2, int& i2) {
  if (v > v1) { v2 = v1; i2 = i1; v1 = v; i1 = i; }
  else if (v > v2) { v2 = v; i2 = i; }
}

// ------ normalize embedding rows: eh = bf16(emb/||row||), enorm = ||row|| --
__global__ __launch_bounds__(256) void norm_e_kernel(
    const float* __restrict__ e, __hip_bfloat16* __restrict__ eh,
    float* __restrict__ enorm) {
  const int k = blockIdx.x;
  const int t = threadIdx.x;
  const float* row = e + (size_t)k * DIM;
  float v[8];
  double ss = 0.0;
#pragma unroll
  for (int j = 0; j < 8; j++) { v[j] = row[t + 256 * j]; ss += (double)v[j] * (double)v[j]; }
  for (int s = 32; s; s >>= 1) ss += __shfl_down(ss, s);
  __shared__ double sb[4];
  __shared__ float snorm;
  if ((t & 63) == 0) sb[t >> 6] = ss;
  __syncthreads();
  if (t == 0) {
    snorm = fmaxf((float)sqrt(sb[0] + sb[1] + sb[2] + sb[3]), 1e-12f);
    enorm[k] = snorm;
  }
  __syncthreads();
  const float nf = snorm;
#pragma unroll
  for (int j = 0; j < 8; j++)
    eh[(size_t)k * DIM + t + 256 * j] = __float2bfloat16(v[j] / nf);
}

// ------ normalize hidden: block per (b,h); coalesced reads over w; LDS -----
// ------ transpose so zh[n][c] (bf16, row-major) writes are coalesced.  -----
__global__ __launch_bounds__(256) void norm_z_kernel(
    const float* __restrict__ hid, __hip_bfloat16* __restrict__ zh) {
  const int bh = blockIdx.x;          // b*32 + h
  const int b = bh >> 5, h = bh & 31;
  const int n0 = bh * 32;             // n = b*1024 + h*32 + w
  const int t = threadIdx.x;
  const int w = t & 31, cp = t >> 5;  // cp 0..7

  __shared__ double ssq[8][32];
  __shared__ float nrm[32];
  __shared__ float tile[32][65];

  // pass 1: sum of squares per w (coalesced over w)
  double acc = 0.0;
  const float* base = hid + ((size_t)b * DIM) * 1024 + h * 32 + w;
#pragma unroll 8
  for (int k = 0; k < 256; k++) {
    float val = base[(size_t)(cp * 256 + k) * 1024];
    acc += (double)val * (double)val;
  }
  ssq[cp][w] = acc;
  __syncthreads();
  if (t < 32) {
    double s = 0.0;
#pragma unroll
    for (int j = 0; j < 8; j++) s += ssq[j][t];
    nrm[t] = fmaxf((float)sqrt(s), 1e-12f);
  }
  __syncthreads();

  // pass 2: re-read, transpose 32w x 64c tiles, write zh coalesced
  for (int ct = 0; ct < 32; ct++) {
    const int c0 = ct * 64;
#pragma unroll
    for (int jt = 0; jt < 8; jt++) {
      const int cl = jt * 8 + cp;
      tile[w][cl] = base[(size_t)(c0 + cl) * 1024];
    }
    __syncthreads();
#pragma unroll
    for (int it = 0; it < 8; it++) {
      const int nl = it * 4 + (t >> 6);
      const int cl = t & 63;
      zh[(size_t)(n0 + nl) * DIM + c0 + cl] =
          __float2bfloat16(tile[nl][cl] / nrm[nl]);
    }
    __syncthreads();
  }
}

// ---------------- bf16 MFMA GEMM (A=zh [NQ][D], B=eh [NK][D]) --------------
// 128x128 tile per block, BK=64, per-(query,ktile) top-2 output.
// v2: double-buffered LDS + 2-phase pipeline (STAGE(next) issued BEFORE
// compute(cur); single __syncthreads per K-step drains vmcnt after the
// MFMAs, so staging latency hides under ds_read+MFMA of the current tile).
// LDS tiles keep the XOR chunk swizzle: row r's 16B chunk c lives at slot
// c^(r&7) (pre-swizzled global source; bank-conflict-free fragment reads).
// XCD-aware bijective block swizzle: each XCD owns a contiguous kb-strip,
// so its 512KB B-panel stays L2-resident.
__global__ __launch_bounds__(256) void gemm_top2(
    const __hip_bfloat16* __restrict__ A, const __hip_bfloat16* __restrict__ B,
    float4* __restrict__ pertile /* [NQ][KTILES] */) {
  __shared__ __align__(16) __hip_bfloat16 As[2][128 * 64];  // 2 x 16KB
  __shared__ __align__(16) __hip_bfloat16 Bs[2][128 * 64];  // 2 x 16KB

  // XCD swizzle: 8192 blocks % 8 == 0 -> simple form is bijective.
  const int bid = blockIdx.x + 64 * blockIdx.y;
  const int swz = (bid & 7) * 1024 + (bid >> 3);
  const int nb = swz & 63;    // query tile
  const int kb = swz >> 6;    // codebook tile (16 consecutive kb per XCD)
  const int n0 = nb * 128;
  const int k0 = kb * 128;

  const int tid  = threadIdx.x;
  const int wid  = tid >> 6;
  const int lane = tid & 63;
  const int wm = wid >> 1, wn = wid & 1;

  const int lr = lane >> 3;             // 0..7 row within staging octet
  const int sc = ((lane & 7) ^ lr) * 8; // swizzled bf16 col offset (chunk^row)
  const int srow = wid * 8 + lr;        // staging row base (per p: +32)

  f32x4 acc[4][4];
#pragma unroll
  for (int i = 0; i < 4; i++)
#pragma unroll
    for (int j = 0; j < 4; j++) acc[i][j] = (f32x4){0.f, 0.f, 0.f, 0.f};

  // issue the 8 global_load_lds for one 128x64 A-tile + B-tile into buffer bufi
#define STAGE(bufi, d0_)                                                      \
  do {                                                                        \
    _Pragma("unroll")                                                         \
    for (int p = 0; p < 4; p++) {                                             \
      const int row = p * 32 + srow;                                          \
      async16(A + (size_t)(n0 + row) * DIM + (d0_) + sc,                      \
              (char*)As[bufi] + p * 4096 + wid * 1024);                       \
      async16(B + (size_t)(k0 + row) * DIM + (d0_) + sc,                      \
              (char*)Bs[bufi] + p * 4096 + wid * 1024);                       \
    }                                                                         \
  } while (0)

  // 16 ds_read_b128 + 32 MFMA on buffer bufi (compile-time constant)
#define COMPUTE(bufi)                                                         \
  do {                                                                        \
    _Pragma("unroll")                                                         \
    for (int kk = 0; kk < 2; kk++) {                                          \
      bf16x8 af[4], bfr[4];                                                   \
      const int cg = kk * 4 + (lane >> 4);                                    \
      _Pragma("unroll")                                                       \
      for (int mi = 0; mi < 4; mi++) {                                        \
        int r = wm * 64 + mi * 16 + (lane & 15);                              \
        af[mi] = *(const bf16x8*)(As[bufi] + r * 64 + ((cg ^ (r & 7)) * 8));  \
      }                                                                       \
      _Pragma("unroll")                                                       \
      for (int ni = 0; ni < 4; ni++) {                                        \
        int r = wn * 64 + ni * 16 + (lane & 15);                              \
        bfr[ni] = *(const bf16x8*)(Bs[bufi] + r * 64 + ((cg ^ (r & 7)) * 8)); \
      }                                                                       \
      _Pragma("unroll")                                                       \
      for (int mi = 0; mi < 4; mi++)                                          \
        _Pragma("unroll")                                                     \
        for (int ni = 0; ni < 4; ni++)                                        \
          acc[mi][ni] = __builtin_amdgcn_mfma_f32_16x16x32_bf16(              \
              af[mi], bfr[ni], acc[mi][ni], 0, 0, 0);                         \
    }                                                                         \
  } while (0)

  // ---- 2-phase pipeline over 32 K-tiles (d0 = t*64), unrolled x2 so the
  // ---- buffer index is static (keeps LDS fragment addresses hoisted).
  STAGE(0, 0);
  __syncthreads();                 // drains vmcnt(0): tile 0 resident
  for (int i = 0; i < 15; i++) {
    const int d0 = i * 128;
    STAGE(1, d0 + 64);             // issue tile 2i+1 loads
    COMPUTE(0);                    // compute tile 2i
    __syncthreads();               // vmcnt(0)+lgkmcnt(0)+barrier
    STAGE(0, d0 + 128);            // issue tile 2i+2 loads
    COMPUTE(1);                    // compute tile 2i+1
    __syncthreads();
  }
  STAGE(1, 1984);                  // tile 31
  COMPUTE(0);                      // tile 30
  __syncthreads();
  COMPUTE(1);                      // tile 31
#undef STAGE
#undef COMPUTE

  // -------- epilogue: per-query-row top-2 over this block's 128 columns ----
  __syncthreads();                       // done reading As/Bs; reuse as buffer
  float4* buf = (float4*)As;             // [128 rows][2 wave-cols]
  const int cbase = k0 + wn * 64 + (lane & 15);
#pragma unroll
  for (int mi = 0; mi < 4; mi++) {
#pragma unroll
    for (int j = 0; j < 4; j++) {
      float v1 = -INFINITY, v2 = -INFINITY;
      int i1 = -1, i2 = -1;
#pragma unroll
      for (int ni = 0; ni < 4; ni++)
        t2_add(acc[mi][ni][j], cbase + ni * 16, v1, i1, v2, i2);
      // reduce across the 16 column-lanes (same rows)
      for (int s = 1; s < 16; s <<= 1) {
        float ov1 = __shfl_xor(v1, s); int oi1 = __shfl_xor(i1, s);
        float ov2 = __shfl_xor(v2, s); int oi2 = __shfl_xor(i2, s);
        t2_add(ov1, oi1, v1, i1, v2, i2);
        t2_add(ov2, oi2, v1, i1, v2, i2);
      }
      if ((lane & 15) == 0) {
        int rl = wm * 64 + mi * 16 + ((lane >> 4) << 2) + j;
        buf[rl * 2 + wn] = make_float4(v1, v2, __int_as_float(i1), __int_as_float(i2));
      }
    }
  }
  __syncthreads();
  if (tid < 128) {
    float4 a = buf[tid * 2 + 0], b = buf[tid * 2 + 1];
    float v1 = a.x, v2 = a.y;
    int i1 = __float_as_int(a.z), i2 = __float_as_int(a.w);
    t2_add(b.x, __float_as_int(b.z), v1, i1, v2, i2);
    t2_add(b.y, __float_as_int(b.w), v1, i1, v2, i2);
    pertile[(size_t)(n0 + tid) * KTILES + kb] =
        make_float4(v1, v2, __int_as_float(i1), __int_as_float(i2));
  }
}

// ------- final argmax: global bf16 max, shortlist within DELTA, fp64 rescore
// Works on RAW hidden/emb: z-norm is a common factor (drops out of argmax);
// e-norm recomputed in fp64 per candidate. sim_rel = dot(z,e)/||e||.
#define DELTA 2e-3f
__global__ __launch_bounds__(256) void rescore_kernel(
    const float4* __restrict__ pertile, const float* __restrict__ hid,
    const float* __restrict__ emb, float* __restrict__ idx_f,
    int* __restrict__ idx_i) {
  const int n = blockIdx.x;
  const int t = threadIdx.x;
  __shared__ double sredd[2][4];
  __shared__ float sm[4];
  __shared__ int sl[128];
  __shared__ int scnt;

  float4 e4 = (t < 128) ? pertile[(size_t)n * KTILES + t]
                        : make_float4(-INFINITY, -INFINITY, 0.f, 0.f);
  float m = e4.x;
  for (int s = 32; s; s >>= 1) m = fmaxf(m, __shfl_xor(m, s));
  if ((t & 63) == 0) sm[t >> 6] = m;
  __syncthreads();
  if (t == 0) {
    sm[0] = fmaxf(fmaxf(sm[0], sm[1]), fmaxf(sm[2], sm[3]));
    scnt = 0;
  }
  __syncthreads();
  const float thr = sm[0] - DELTA;
  if (t < 128) {
    if (e4.x >= thr) { int p = atomicAdd(&scnt, 1); if (p < 128) sl[p] = __float_as_int(e4.z); }
    if (e4.y >= thr) { int p = atomicAdd(&scnt, 1); if (p < 128) sl[p] = __float_as_int(e4.w); }
  }
  __syncthreads();
  const int cnt = min(scnt, 128);

  // load raw z row (strided; n = b*1024 + hw)
  const int b = n >> 10, hw = n & 1023;
  const float* zbase = hid + (size_t)b * DIM * 1024 + hw;
  double zv[8];
#pragma unroll
  for (int j = 0; j < 8; j++) zv[j] = (double)zbase[(size_t)(t + 256 * j) * 1024];

  double bestv = -1e300;
  int besti = 0x7fffffff;
  for (int c = 0; c < cnt; c++) {
    const int k = sl[c];
    const float* erow = emb + (size_t)k * DIM;
    double dot = 0.0, ee = 0.0;
#pragma unroll
    for (int j = 0; j < 8; j++) {
      double ev = (double)erow[t + 256 * j];
      dot += zv[j] * ev;
      ee  += ev * ev;
    }
    for (int s = 32; s; s >>= 1) { dot += __shfl_down(dot, s); ee += __shfl_down(ee, s); }
    if ((t & 63) == 0) { sredd[0][t >> 6] = dot; sredd[1][t >> 6] = ee; }
    __syncthreads();
    if (t == 0) {
      double td = sredd[0][0] + sredd[0][1] + sredd[0][2] + sredd[0][3];
      double te = sredd[1][0] + sredd[1][1] + sredd[1][2] + sredd[1][3];
      double sim = td / sqrt(te);
      if (sim > bestv || (sim == bestv && k < besti)) { bestv = sim; besti = k; }
    }
    __syncthreads();
  }
  if (t == 0) { idx_f[n] = (float)besti; idx_i[n] = besti; }
}

// ------- gather emb[idx]/norm back to NCHW via LDS transpose ---------------
__global__ __launch_bounds__(256) void gather_kernel(
    const float* __restrict__ emb, const float* __restrict__ enorm,
    const int* __restrict__ idx, float* __restrict__ out) {
  const int bh = blockIdx.x;          // b*32 + h
  const int b = bh >> 5, h = bh & 31;
  const int n0 = bh * 32;
  const int c0 = blockIdx.y * 64;
  const int t = threadIdx.x;

  __shared__ int rows[32];
  __shared__ float nrm[32];
  __shared__ float tile[32][65];

  if (t < 32) {
    int r = idx[n0 + t];
    rows[t] = r;
    nrm[t] = enorm[r];
  }
  __syncthreads();
#pragma unroll
  for (int it = 0; it < 8; it++) {
    const int nl = it * 4 + (t >> 6);
    const int cl = t & 63;
    tile[nl][cl] = emb[(size_t)rows[nl] * DIM + c0 + cl] / nrm[nl];
  }
  __syncthreads();
#pragma unroll
  for (int jt = 0; jt < 8; jt++) {
    const int cl = jt * 8 + (t >> 5);
    const int w = t & 31;
    out[((size_t)(b * DIM + c0 + cl) << 10) + (h << 5) + w] = tile[w][cl];
  }
}

extern "C" void kernel_launch(void* const* d_in, const int* in_sizes, int n_in,
                              void* d_out, int out_size, void* d_ws, size_t ws_size,
                              hipStream_t stream) {
  const float* hidden = (const float*)d_in[0];  // (8,2048,32,32) fp32
  const float* emb    = (const float*)d_in[1];  // (16384,2048) fp32
  float* out = (float*)d_out;

  // workspace layout (~118 MB total)
  char* ws = (char*)d_ws;
  __hip_bfloat16* eh = (__hip_bfloat16*)ws; ws += (size_t)NK * DIM * 2;   // 67.1 MB
  __hip_bfloat16* zh = (__hip_bfloat16*)ws; ws += (size_t)NQ * DIM * 2;   // 33.6 MB
  float4* pertile = (float4*)ws;            ws += (size_t)NQ * KTILES * 16; // 16.8 MB
  float* enorm = (float*)ws;                ws += (size_t)NK * 4;         // 64 KB
  int* idxi = (int*)ws;                     ws += (size_t)NQ * 4;         // 32 KB

  norm_e_kernel<<<NK, 256, 0, stream>>>(emb, eh, enorm);
  norm_z_kernel<<<256, 256, 0, stream>>>(hidden, zh);
  gemm_top2<<<dim3(NQ / 128, KTILES), 256, 0, stream>>>(zh, eh, pertile);
  rescore_kernel<<<NQ, 256, 0, stream>>>(pertile, hidden, emb, out + QUANT_ELEMS, idxi);
  gather_kernel<<<dim3(256, DIM / 64), 256, 0, stream>>>(emb, enorm, idxi, out);
}

// Round 3
// 2096.773 us; speedup vs baseline: 1.0821x; 1.0821x over previous
//
#include <hip/hip_runtime.h>
#include <hip/hip_bf16.h>

// Problem constants
#define NQ   8192      // B*H*W = 8*32*32 queries
#define NK   16384     // codebook entries
#define DIM  2048      // embedding dim
#define KTILES 128     // NK / 128 (pertile granularity, unchanged)
#define QUANT_ELEMS (8*2048*32*32)  // 16777216

typedef __attribute__((ext_vector_type(8))) short bf16x8;
typedef __attribute__((ext_vector_type(4))) float f32x4;

// ---------------- async global->LDS 16B copy (wave-uniform LDS base) -------
__device__ __forceinline__ void async16(const void* g, void* lds) {
  __builtin_amdgcn_global_load_lds(
      (const __attribute__((address_space(1))) unsigned int*)g,
      (__attribute__((address_space(3))) unsigned int*)lds,
      16, 0, 0);
}

// ---------------- top-2 helper --------------------------------------------
__device__ __forceinline__ void t2_add(float v, int i,
                                       float& v1, int& i1, float& v2, int& i2) {
  if (v > v1) { v2 = v1; i2 = i1; v1 = v; i1 = i; }
  else if (v > v2) { v2 = v; i2 = i; }
}

// ------ normalize embedding rows: eh = bf16(emb/||row||), enorm = ||row|| --
__global__ __launch_bounds__(256) void norm_e_kernel(
    const float* __restrict__ e, __hip_bfloat16* __restrict__ eh,
    float* __restrict__ enorm) {
  const int k = blockIdx.x;
  const int t = threadIdx.x;
  const float* row = e + (size_t)k * DIM;
  float v[8];
  double ss = 0.0;
#pragma unroll
  for (int j = 0; j < 8; j++) { v[j] = row[t + 256 * j]; ss += (double)v[j] * (double)v[j]; }
  for (int s = 32; s; s >>= 1) ss += __shfl_down(ss, s);
  __shared__ double sb[4];
  __shared__ float snorm;
  if ((t & 63) == 0) sb[t >> 6] = ss;
  __syncthreads();
  if (t == 0) {
    snorm = fmaxf((float)sqrt(sb[0] + sb[1] + sb[2] + sb[3]), 1e-12f);
    enorm[k] = snorm;
  }
  __syncthreads();
  const float nf = snorm;
#pragma unroll
  for (int j = 0; j < 8; j++)
    eh[(size_t)k * DIM + t + 256 * j] = __float2bfloat16(v[j] / nf);
}

// ------ normalize hidden: block per (b,h); coalesced reads over w; LDS -----
// ------ transpose so zh[n][c] (bf16, row-major) writes are coalesced.  -----
__global__ __launch_bounds__(256) void norm_z_kernel(
    const float* __restrict__ hid, __hip_bfloat16* __restrict__ zh) {
  const int bh = blockIdx.x;          // b*32 + h
  const int b = bh >> 5, h = bh & 31;
  const int n0 = bh * 32;             // n = b*1024 + h*32 + w
  const int t = threadIdx.x;
  const int w = t & 31, cp = t >> 5;  // cp 0..7

  __shared__ double ssq[8][32];
  __shared__ float nrm[32];
  __shared__ float tile[32][65];

  // pass 1: sum of squares per w (coalesced over w)
  double acc = 0.0;
  const float* base = hid + ((size_t)b * DIM) * 1024 + h * 32 + w;
#pragma unroll 8
  for (int k = 0; k < 256; k++) {
    float val = base[(size_t)(cp * 256 + k) * 1024];
    acc += (double)val * (double)val;
  }
  ssq[cp][w] = acc;
  __syncthreads();
  if (t < 32) {
    double s = 0.0;
#pragma unroll
    for (int j = 0; j < 8; j++) s += ssq[j][t];
    nrm[t] = fmaxf((float)sqrt(s), 1e-12f);
  }
  __syncthreads();

  // pass 2: re-read, transpose 32w x 64c tiles, write zh coalesced
  for (int ct = 0; ct < 32; ct++) {
    const int c0 = ct * 64;
#pragma unroll
    for (int jt = 0; jt < 8; jt++) {
      const int cl = jt * 8 + cp;
      tile[w][cl] = base[(size_t)(c0 + cl) * 1024];
    }
    __syncthreads();
#pragma unroll
    for (int it = 0; it < 8; it++) {
      const int nl = it * 4 + (t >> 6);
      const int cl = t & 63;
      zh[(size_t)(n0 + nl) * DIM + c0 + cl] =
          __float2bfloat16(tile[nl][cl] / nrm[nl]);
    }
    __syncthreads();
  }
}

// ---------------- bf16 MFMA GEMM (A=zh [NQ][D], B=eh [NK][D]) --------------
// v3: 256x256 tile per block, BK=64, 8 waves (512 thr, 2M x 4N), 128KB LDS
// double-buffer, 2-phase pipeline: STAGE(next) issued BEFORE COMPUTE(cur),
// single __syncthreads per K-step (full-drain semantics -> race-free).
// No XCD swizzle (round-2 showed it 3x'd FETCH_SIZE: per-XCD A-streaming
// blows the 4MB L2). Natural order: consecutive blocks share one B-tile.
// LDS keeps the XOR chunk swizzle: row r's 16B chunk c at slot c^(r&7)
// (pre-swizzled global source; bank-conflict-free ds_read_b128).
// Epilogue: top-2 per 128-column HALF-tile, so pertile stays [NQ][128] and
// rescore/gather are unchanged.
__global__ __launch_bounds__(512, 2) void gemm_top2(
    const __hip_bfloat16* __restrict__ A, const __hip_bfloat16* __restrict__ B,
    float4* __restrict__ pertile /* [NQ][KTILES] */) {
  __shared__ __align__(16) __hip_bfloat16 As[2][256 * 64];  // 2 x 32KB
  __shared__ __align__(16) __hip_bfloat16 Bs[2][256 * 64];  // 2 x 32KB

  const int nb = blockIdx.x;   // 0..31  (query tile, fast dim -> B shared)
  const int kb = blockIdx.y;   // 0..63  (codebook tile of 256)
  const int n0 = nb * 256;
  const int k0 = kb * 256;

  const int tid  = threadIdx.x;
  const int wid  = tid >> 6;           // 0..7
  const int lane = tid & 63;
  const int wm = wid >> 2;             // 0..1  row block (128 rows)
  const int wn = wid & 3;              // 0..3  col block (64 cols)

  const int lr = lane >> 3;             // 0..7 row within staging octet
  const int sc = ((lane & 7) ^ lr) * 8; // swizzled bf16 col offset (chunk^row)
  const int srow = wid * 8 + lr;        // staging row base (per q: +64)

  f32x4 acc[8][4];
#pragma unroll
  for (int i = 0; i < 8; i++)
#pragma unroll
    for (int j = 0; j < 4; j++) acc[i][j] = (f32x4){0.f, 0.f, 0.f, 0.f};

  // 8 global_load_lds per thread: 256x64 A-tile + B-tile into buffer bufi
#define STAGE(bufi, d0_)                                                      \
  do {                                                                        \
    _Pragma("unroll")                                                         \
    for (int q = 0; q < 4; q++) {                                             \
      const int row = q * 64 + srow;                                          \
      async16(A + (size_t)(n0 + row) * DIM + (d0_) + sc,                      \
              (char*)As[bufi] + q * 8192 + wid * 1024);                       \
      async16(B + (size_t)(k0 + row) * DIM + (d0_) + sc,                      \
              (char*)Bs[bufi] + q * 8192 + wid * 1024);                       \
    }                                                                         \
  } while (0)

  // 24 ds_read_b128 + 64 MFMA per wave on buffer bufi
#define COMPUTE(bufi)                                                         \
  do {                                                                        \
    _Pragma("unroll")                                                         \
    for (int kk = 0; kk < 2; kk++) {                                          \
      bf16x8 af[8], bfr[4];                                                   \
      const int cg = kk * 4 + (lane >> 4);                                    \
      _Pragma("unroll")                                                       \
      for (int mi = 0; mi < 8; mi++) {                                        \
        int r = wm * 128 + mi * 16 + (lane & 15);                             \
        af[mi] = *(const bf16x8*)(As[bufi] + r * 64 + ((cg ^ (r & 7)) * 8));  \
      }                                                                       \
      _Pragma("unroll")                                                       \
      for (int ni = 0; ni < 4; ni++) {                                        \
        int r = wn * 64 + ni * 16 + (lane & 15);                              \
        bfr[ni] = *(const bf16x8*)(Bs[bufi] + r * 64 + ((cg ^ (r & 7)) * 8)); \
      }                                                                       \
      _Pragma("unroll")                                                       \
      for (int mi = 0; mi < 8; mi++)                                          \
        _Pragma("unroll")                                                     \
        for (int ni = 0; ni < 4; ni++)                                        \
          acc[mi][ni] = __builtin_amdgcn_mfma_f32_16x16x32_bf16(              \
              af[mi], bfr[ni], acc[mi][ni], 0, 0, 0);                         \
    }                                                                         \
  } while (0)

  // ---- 2-phase pipeline over 32 K-tiles (d0 = t*64), unrolled x2 so the
  // ---- buffer index is static.
  STAGE(0, 0);
  __syncthreads();                 // drains vmcnt(0): tile 0 resident
  for (int i = 0; i < 15; i++) {
    const int d0 = i * 128;
    STAGE(1, d0 + 64);             // issue tile 2i+1 loads
    COMPUTE(0);                    // compute tile 2i
    __syncthreads();               // vmcnt(0)+lgkmcnt(0)+barrier
    STAGE(0, d0 + 128);            // issue tile 2i+2 loads
    COMPUTE(1);                    // compute tile 2i+1
    __syncthreads();
  }
  STAGE(1, 1984);                  // tile 31
  COMPUTE(0);                      // tile 30
  __syncthreads();
  COMPUTE(1);                      // tile 31
#undef STAGE
#undef COMPUTE

  // -------- epilogue: per-query-row top-2 per 128-col HALF of this tile ----
  __syncthreads();                       // done reading As/Bs; reuse as buffer
  float4* buf = (float4*)As;             // [256 rows][4 wave-cols] = 16KB
  const int cbase = k0 + wn * 64 + (lane & 15);
#pragma unroll
  for (int mi = 0; mi < 8; mi++) {
#pragma unroll
    for (int j = 0; j < 4; j++) {
      float v1 = -INFINITY, v2 = -INFINITY;
      int i1 = -1, i2 = -1;
#pragma unroll
      for (int ni = 0; ni < 4; ni++)
        t2_add(acc[mi][ni][j], cbase + ni * 16, v1, i1, v2, i2);
      // reduce across the 16 column-lanes (same rows)
      for (int s = 1; s < 16; s <<= 1) {
        float ov1 = __shfl_xor(v1, s); int oi1 = __shfl_xor(i1, s);
        float ov2 = __shfl_xor(v2, s); int oi2 = __shfl_xor(i2, s);
        t2_add(ov1, oi1, v1, i1, v2, i2);
        t2_add(ov2, oi2, v1, i1, v2, i2);
      }
      if ((lane & 15) == 0) {
        int rl = wm * 128 + mi * 16 + ((lane >> 4) << 2) + j;
        buf[rl * 4 + wn] = make_float4(v1, v2, __int_as_float(i1), __int_as_float(i2));
      }
    }
  }
  __syncthreads();
  // combine wave-col pairs: (wn 0,1) -> half 0, (wn 2,3) -> half 1
  {
    const int row = tid >> 1, half = tid & 1;
    float4 a = buf[row * 4 + half * 2 + 0], b = buf[row * 4 + half * 2 + 1];
    float v1 = a.x, v2 = a.y;
    int i1 = __float_as_int(a.z), i2 = __float_as_int(a.w);
    t2_add(b.x, __float_as_int(b.z), v1, i1, v2, i2);
    t2_add(b.y, __float_as_int(b.w), v1, i1, v2, i2);
    pertile[(size_t)(n0 + row) * KTILES + kb * 2 + half] =
        make_float4(v1, v2, __int_as_float(i1), __int_as_float(i2));
  }
}

// ------- final argmax: global bf16 max, shortlist within DELTA, fp64 rescore
// Works on RAW hidden/emb: z-norm is a common factor (drops out of argmax);
// e-norm recomputed in fp64 per candidate. sim_rel = dot(z,e)/||e||.
#define DELTA 2e-3f
__global__ __launch_bounds__(256) void rescore_kernel(
    const float4* __restrict__ pertile, const float* __restrict__ hid,
    const float* __restrict__ emb, float* __restrict__ idx_f,
    int* __restrict__ idx_i) {
  const int n = blockIdx.x;
  const int t = threadIdx.x;
  __shared__ double sredd[2][4];
  __shared__ float sm[4];
  __shared__ int sl[128];
  __shared__ int scnt;

  float4 e4 = (t < 128) ? pertile[(size_t)n * KTILES + t]
                        : make_float4(-INFINITY, -INFINITY, 0.f, 0.f);
  float m = e4.x;
  for (int s = 32; s; s >>= 1) m = fmaxf(m, __shfl_xor(m, s));
  if ((t & 63) == 0) sm[t >> 6] = m;
  __syncthreads();
  if (t == 0) {
    sm[0] = fmaxf(fmaxf(sm[0], sm[1]), fmaxf(sm[2], sm[3]));
    scnt = 0;
  }
  __syncthreads();
  const float thr = sm[0] - DELTA;
  if (t < 128) {
    if (e4.x >= thr) { int p = atomicAdd(&scnt, 1); if (p < 128) sl[p] = __float_as_int(e4.z); }
    if (e4.y >= thr) { int p = atomicAdd(&scnt, 1); if (p < 128) sl[p] = __float_as_int(e4.w); }
  }
  __syncthreads();
  const int cnt = min(scnt, 128);

  // load raw z row (strided; n = b*1024 + hw)
  const int b = n >> 10, hw = n & 1023;
  const float* zbase = hid + (size_t)b * DIM * 1024 + hw;
  double zv[8];
#pragma unroll
  for (int j = 0; j < 8; j++) zv[j] = (double)zbase[(size_t)(t + 256 * j) * 1024];

  double bestv = -1e300;
  int besti = 0x7fffffff;
  for (int c = 0; c < cnt; c++) {
    const int k = sl[c];
    const float* erow = emb + (size_t)k * DIM;
    double dot = 0.0, ee = 0.0;
#pragma unroll
    for (int j = 0; j < 8; j++) {
      double ev = (double)erow[t + 256 * j];
      dot += zv[j] * ev;
      ee  += ev * ev;
    }
    for (int s = 32; s; s >>= 1) { dot += __shfl_down(dot, s); ee += __shfl_down(ee, s); }
    if ((t & 63) == 0) { sredd[0][t >> 6] = dot; sredd[1][t >> 6] = ee; }
    __syncthreads();
    if (t == 0) {
      double td = sredd[0][0] + sredd[0][1] + sredd[0][2] + sredd[0][3];
      double te = sredd[1][0] + sredd[1][1] + sredd[1][2] + sredd[1][3];
      double sim = td / sqrt(te);
      if (sim > bestv || (sim == bestv && k < besti)) { bestv = sim; besti = k; }
    }
    __syncthreads();
  }
  if (t == 0) { idx_f[n] = (float)besti; idx_i[n] = besti; }
}

// ------- gather emb[idx]/norm back to NCHW via LDS transpose ---------------
__global__ __launch_bounds__(256) void gather_kernel(
    const float* __restrict__ emb, const float* __restrict__ enorm,
    const int* __restrict__ idx, float* __restrict__ out) {
  const int bh = blockIdx.x;          // b*32 + h
  const int b = bh >> 5, h = bh & 31;
  const int n0 = bh * 32;
  const int c0 = blockIdx.y * 64;
  const int t = threadIdx.x;

  __shared__ int rows[32];
  __shared__ float nrm[32];
  __shared__ float tile[32][65];

  if (t < 32) {
    int r = idx[n0 + t];
    rows[t] = r;
    nrm[t] = enorm[r];
  }
  __syncthreads();
#pragma unroll
  for (int it = 0; it < 8; it++) {
    const int nl = it * 4 + (t >> 6);
    const int cl = t & 63;
    tile[nl][cl] = emb[(size_t)rows[nl] * DIM + c0 + cl] / nrm[nl];
  }
  __syncthreads();
#pragma unroll
  for (int jt = 0; jt < 8; jt++) {
    const int cl = jt * 8 + (t >> 5);
    const int w = t & 31;
    out[((size_t)(b * DIM + c0 + cl) << 10) + (h << 5) + w] = tile[w][cl];
  }
}

extern "C" void kernel_launch(void* const* d_in, const int* in_sizes, int n_in,
                              void* d_out, int out_size, void* d_ws, size_t ws_size,
                              hipStream_t stream) {
  const float* hidden = (const float*)d_in[0];  // (8,2048,32,32) fp32
  const float* emb    = (const float*)d_in[1];  // (16384,2048) fp32
  float* out = (float*)d_out;

  // workspace layout (~118 MB total)
  char* ws = (char*)d_ws;
  __hip_bfloat16* eh = (__hip_bfloat16*)ws; ws += (size_t)NK * DIM * 2;   // 67.1 MB
  __hip_bfloat16* zh = (__hip_bfloat16*)ws; ws += (size_t)NQ * DIM * 2;   // 33.6 MB
  float4* pertile = (float4*)ws;            ws += (size_t)NQ * KTILES * 16; // 16.8 MB
  float* enorm = (float*)ws;                ws += (size_t)NK * 4;         // 64 KB
  int* idxi = (int*)ws;                     ws += (size_t)NQ * 4;         // 32 KB

  norm_e_kernel<<<NK, 256, 0, stream>>>(emb, eh, enorm);
  norm_z_kernel<<<256, 256, 0, stream>>>(hidden, zh);
  gemm_top2<<<dim3(NQ / 256, NK / 256), 512, 0, stream>>>(zh, eh, pertile);
  rescore_kernel<<<NQ, 256, 0, stream>>>(pertile, hidden, emb, out + QUANT_ELEMS, idxi);
  gather_kernel<<<dim3(256, DIM / 64), 256, 0, stream>>>(emb, enorm, idxi, out);
}

// Round 4
// 1842.559 us; speedup vs baseline: 1.2314x; 1.1380x over previous
//
#include <hip/hip_runtime.h>
#include <hip/hip_bf16.h>

// Problem constants
#define NQ   8192      // B*H*W = 8*32*32 queries
#define NK   16384     // codebook entries
#define DIM  2048      // embedding dim
#define KTILES 128     // NK / 128 (pertile granularity, unchanged)
#define QUANT_ELEMS (8*2048*32*32)  // 16777216

typedef __attribute__((ext_vector_type(8))) short bf16x8;
typedef __attribute__((ext_vector_type(4))) float f32x4;

// ---------------- async global->LDS 16B copy (wave-uniform LDS base) -------
__device__ __forceinline__ void async16(const void* g, void* lds) {
  __builtin_amdgcn_global_load_lds(
      (const __attribute__((address_space(1))) unsigned int*)g,
      (__attribute__((address_space(3))) unsigned int*)lds,
      16, 0, 0);
}

// ---------------- top-2 helper --------------------------------------------
__device__ __forceinline__ void t2_add(float v, int i,
                                       float& v1, int& i1, float& v2, int& i2) {
  if (v > v1) { v2 = v1; i2 = i1; v1 = v; i1 = i; }
  else if (v > v2) { v2 = v; i2 = i; }
}

// ------ normalize embedding rows: eh = bf16(emb/||row||), enorm = ||row|| --
__global__ __launch_bounds__(256) void norm_e_kernel(
    const float* __restrict__ e, __hip_bfloat16* __restrict__ eh,
    float* __restrict__ enorm) {
  const int k = blockIdx.x;
  const int t = threadIdx.x;
  const float* row = e + (size_t)k * DIM;
  float v[8];
  double ss = 0.0;
#pragma unroll
  for (int j = 0; j < 8; j++) { v[j] = row[t + 256 * j]; ss += (double)v[j] * (double)v[j]; }
  for (int s = 32; s; s >>= 1) ss += __shfl_down(ss, s);
  __shared__ double sb[4];
  __shared__ float snorm;
  if ((t & 63) == 0) sb[t >> 6] = ss;
  __syncthreads();
  if (t == 0) {
    snorm = fmaxf((float)sqrt(sb[0] + sb[1] + sb[2] + sb[3]), 1e-12f);
    enorm[k] = snorm;
  }
  __syncthreads();
  const float nf = snorm;
#pragma unroll
  for (int j = 0; j < 8; j++)
    eh[(size_t)k * DIM + t + 256 * j] = __float2bfloat16(v[j] / nf);
}

// ------ normalize hidden: block per (b,h); coalesced reads over w; LDS -----
// ------ transpose so zh[n][c] (bf16, row-major) writes are coalesced.  -----
__global__ __launch_bounds__(256) void norm_z_kernel(
    const float* __restrict__ hid, __hip_bfloat16* __restrict__ zh) {
  const int bh = blockIdx.x;          // b*32 + h
  const int b = bh >> 5, h = bh & 31;
  const int n0 = bh * 32;             // n = b*1024 + h*32 + w
  const int t = threadIdx.x;
  const int w = t & 31, cp = t >> 5;  // cp 0..7

  __shared__ double ssq[8][32];
  __shared__ float nrm[32];
  __shared__ float tile[32][65];

  // pass 1: sum of squares per w (coalesced over w)
  double acc = 0.0;
  const float* base = hid + ((size_t)b * DIM) * 1024 + h * 32 + w;
#pragma unroll 8
  for (int k = 0; k < 256; k++) {
    float val = base[(size_t)(cp * 256 + k) * 1024];
    acc += (double)val * (double)val;
  }
  ssq[cp][w] = acc;
  __syncthreads();
  if (t < 32) {
    double s = 0.0;
#pragma unroll
    for (int j = 0; j < 8; j++) s += ssq[j][t];
    nrm[t] = fmaxf((float)sqrt(s), 1e-12f);
  }
  __syncthreads();

  // pass 2: re-read, transpose 32w x 64c tiles, write zh coalesced
  for (int ct = 0; ct < 32; ct++) {
    const int c0 = ct * 64;
#pragma unroll
    for (int jt = 0; jt < 8; jt++) {
      const int cl = jt * 8 + cp;
      tile[w][cl] = base[(size_t)(c0 + cl) * 1024];
    }
    __syncthreads();
#pragma unroll
    for (int it = 0; it < 8; it++) {
      const int nl = it * 4 + (t >> 6);
      const int cl = t & 63;
      zh[(size_t)(n0 + nl) * DIM + c0 + cl] =
          __float2bfloat16(tile[nl][cl] / nrm[nl]);
    }
    __syncthreads();
  }
}

// ---------------- bf16 MFMA GEMM (A=zh [NQ][D], B=eh [NK][D]) --------------
// v4: 256x256 tile, BK=64, 8 waves; 4-phase counted-vmcnt schedule (T3+T4+T5).
// Per tile: 4 phases, each {ds_read subtile; issue stage unit for t+1 into
// the OTHER buffer; raw s_barrier; asm lgkmcnt(0); setprio(1); 16 MFMA;
// setprio(0); raw s_barrier}. Stage unit order per tile:
//   [B rows 0-127] [B rows 128-255] [A quad-pair 0,1] [A quad-pair 2,3]
// Checkpoints (inline asm, counted, NEVER 0 in main loop):
//   pre-p0: vmcnt(2)  (retires B0,B1,Aq0,Aq1 of current tile)
//   pre-p2: vmcnt(4)  (retires Aq2,Aq3 of current tile)
// Every wait targets loads issued >=2 phases earlier; loads stay in flight
// across barriers (the m218 mechanism). Volatile-asm memory clobbers at each
// phase boundary pin global_load_lds issue order (vmcnt counting integrity).
// LDS XOR chunk swizzle unchanged (slot = chunk^(row&7), conflict-free).
// Accumulation order per acc[mi][ni] identical to v3 -> bitwise-same output.
__global__ __launch_bounds__(512, 2) void gemm_top2(
    const __hip_bfloat16* __restrict__ A, const __hip_bfloat16* __restrict__ B,
    float4* __restrict__ pertile /* [NQ][KTILES] */) {
  __shared__ __align__(16) __hip_bfloat16 As[2][256 * 64];  // 2 x 32KB
  __shared__ __align__(16) __hip_bfloat16 Bs[2][256 * 64];  // 2 x 32KB

  const int nb = blockIdx.x;   // 0..31  (query tile; fast dim -> B-tile shared)
  const int kb = blockIdx.y;   // 0..63  (codebook tile of 256)
  const int n0 = nb * 256;
  const int k0 = kb * 256;

  const int tid  = threadIdx.x;
  const int wid  = tid >> 6;           // 0..7
  const int lane = tid & 63;
  const int wm = wid >> 2;             // 0..1  row block (128 rows)
  const int wn = wid & 3;              // 0..3  col block (64 cols)

  const int lr = lane >> 3;             // 0..7 row within staging octet
  const int sc = ((lane & 7) ^ lr) * 8; // swizzled bf16 col offset (chunk^row)

  const int la15 = lane & 15;
  const int rba  = wm * 128 + la15;     // A fragment row base
  const int rbb  = wn * 64 + la15;      // B fragment row base
  const int slot0 = (((lane >> 4) ^ (lane & 7)) * 8);        // kk=0 chunk slot
  const int slot1 = (((4 + (lane >> 4)) ^ (lane & 7)) * 8);  // kk=1 chunk slot

  f32x4 acc[8][4];
#pragma unroll
  for (int i = 0; i < 8; i++)
#pragma unroll
    for (int j = 0; j < 4; j++) acc[i][j] = (f32x4){0.f, 0.f, 0.f, 0.f};

  bf16x8 af[2][2];     // A frags: [m in quad][kk]
  bf16x8 bfr[4][2];    // B frags: [ni][kk], live across the tile's 4 phases

  // ---- stage units (2 loads for a B-half, 1 load for an A-quad) ----------
#define STAGE_BU(BUF, d0_, h)                                                 \
  do {                                                                        \
    _Pragma("unroll")                                                         \
    for (int j_ = 0; j_ < 2; j_++) {                                          \
      const int row_ = (h) * 128 + j_ * 64 + wid * 8 + lr;                    \
      async16(B + (size_t)(k0 + row_) * DIM + (d0_) + sc,                     \
              (char*)&Bs[BUF][0] + (h) * 16384 + j_ * 8192 + wid * 1024);     \
    }                                                                         \
  } while (0)

#define STAGE_A1(BUF, d0_, i_)                                                \
  do {                                                                        \
    const int row_ = (wid < 4) ? ((i_) * 32 + wid * 8 + lr)                   \
                               : (128 + (i_) * 32 + (wid - 4) * 8 + lr);      \
    const int lb_  = (wid < 4) ? ((i_) * 4096 + wid * 1024)                   \
                               : (16384 + (i_) * 4096 + (wid - 4) * 1024);    \
    async16(A + (size_t)(n0 + row_) * DIM + (d0_) + sc,                       \
            (char*)&As[BUF][0] + lb_);                                        \
  } while (0)

#define AF_LOAD(BUF, q)                                                       \
  do {                                                                        \
    _Pragma("unroll")                                                         \
    for (int m_ = 0; m_ < 2; m_++) {                                          \
      af[m_][0] = *(const bf16x8*)(&As[BUF][(rba + (q)*32 + m_*16)*64 + slot0]); \
      af[m_][1] = *(const bf16x8*)(&As[BUF][(rba + (q)*32 + m_*16)*64 + slot1]); \
    }                                                                         \
  } while (0)

#define BF_LOAD(BUF)                                                          \
  do {                                                                        \
    _Pragma("unroll")                                                         \
    for (int n_ = 0; n_ < 4; n_++) {                                          \
      bfr[n_][0] = *(const bf16x8*)(&Bs[BUF][(rbb + n_*16)*64 + slot0]);      \
      bfr[n_][1] = *(const bf16x8*)(&Bs[BUF][(rbb + n_*16)*64 + slot1]);      \
    }                                                                         \
  } while (0)

#define MFMA_Q(q)                                                             \
  do {                                                                        \
    __builtin_amdgcn_s_setprio(1);                                            \
    _Pragma("unroll")                                                         \
    for (int kk_ = 0; kk_ < 2; kk_++)                                         \
      _Pragma("unroll")                                                       \
      for (int m_ = 0; m_ < 2; m_++)                                          \
        _Pragma("unroll")                                                     \
        for (int n_ = 0; n_ < 4; n_++)                                        \
          acc[(q)*2 + m_][n_] = __builtin_amdgcn_mfma_f32_16x16x32_bf16(      \
              af[m_][kk_], bfr[n_][kk_], acc[(q)*2 + m_][n_], 0, 0, 0);       \
    __builtin_amdgcn_s_setprio(0);                                            \
  } while (0)

#define LGKM0 asm volatile("s_waitcnt lgkmcnt(0)" ::: "memory")
#define BAR   __builtin_amdgcn_s_barrier()
#define SB0   __builtin_amdgcn_sched_barrier(0)

  // steady-state tile: read BUF, stage tile t+1 (global col d0n_) into !BUF
#define TILE_MAIN(BUF, d0n_)                                                  \
  do {                                                                        \
    /* p0 */                                                                  \
    asm volatile("s_waitcnt vmcnt(2)" ::: "memory");                          \
    BAR;                                                                      \
    BF_LOAD(BUF); AF_LOAD(BUF, 0);                                            \
    STAGE_BU(1 - (BUF), (d0n_), 0);                                           \
    LGKM0; MFMA_Q(0); BAR;                                                    \
    /* p1 */                                                                  \
    BAR;                                                                      \
    AF_LOAD(BUF, 1);                                                          \
    STAGE_BU(1 - (BUF), (d0n_), 1);                                           \
    LGKM0; MFMA_Q(1); BAR;                                                    \
    /* p2 */                                                                  \
    asm volatile("s_waitcnt vmcnt(4)" ::: "memory");                          \
    BAR;                                                                      \
    AF_LOAD(BUF, 2);                                                          \
    STAGE_A1(1 - (BUF), (d0n_), 0); STAGE_A1(1 - (BUF), (d0n_), 1);           \
    LGKM0; MFMA_Q(2); BAR;                                                    \
    /* p3 */                                                                  \
    BAR;                                                                      \
    AF_LOAD(BUF, 3);                                                          \
    STAGE_A1(1 - (BUF), (d0n_), 2); STAGE_A1(1 - (BUF), (d0n_), 3);           \
    LGKM0; MFMA_Q(3); BAR;                                                    \
  } while (0)

  // last tile: no staging; drain progressively (2, -, 0, -)
#define TILE_LAST(BUF)                                                        \
  do {                                                                        \
    asm volatile("s_waitcnt vmcnt(2)" ::: "memory");                          \
    BAR;                                                                      \
    BF_LOAD(BUF); AF_LOAD(BUF, 0); LGKM0; MFMA_Q(0); BAR;                     \
    BAR;                                                                      \
    AF_LOAD(BUF, 1); LGKM0; MFMA_Q(1); BAR;                                   \
    asm volatile("s_waitcnt vmcnt(0)" ::: "memory");                          \
    BAR;                                                                      \
    AF_LOAD(BUF, 2); LGKM0; MFMA_Q(2); BAR;                                   \
    BAR;                                                                      \
    AF_LOAD(BUF, 3); LGKM0; MFMA_Q(3); BAR;                                   \
  } while (0)

  // ---- prologue: stage tile 0 into buffer 0, unit order pinned -----------
  STAGE_BU(0, 0, 0); SB0;
  STAGE_BU(0, 0, 1); SB0;
  STAGE_A1(0, 0, 0); STAGE_A1(0, 0, 1); SB0;
  STAGE_A1(0, 0, 2); STAGE_A1(0, 0, 3);

  // ---- main loop: tiles 0..29 (pairs), 30, 31 ----------------------------
#pragma unroll 1
  for (int i = 0; i < 15; i++) {
    TILE_MAIN(0, i * 128 + 64);    // tile 2i   (buf0), stage 2i+1 -> buf1
    TILE_MAIN(1, i * 128 + 128);   // tile 2i+1 (buf1), stage 2i+2 -> buf0
  }
  TILE_MAIN(0, 1984);              // tile 30 (buf0), stage 31 -> buf1
  TILE_LAST(1);                    // tile 31 (buf1)

#undef TILE_MAIN
#undef TILE_LAST
#undef STAGE_BU
#undef STAGE_A1
#undef AF_LOAD
#undef BF_LOAD
#undef MFMA_Q
#undef LGKM0
#undef BAR
#undef SB0

  // -------- epilogue: per-query-row top-2 per 128-col HALF of this tile ----
  __syncthreads();                       // all reads done; reuse As as buffer
  float4* buf = (float4*)As;             // [256 rows][4 wave-cols] = 16KB
  const int cbase = k0 + wn * 64 + (lane & 15);
#pragma unroll
  for (int mi = 0; mi < 8; mi++) {
#pragma unroll
    for (int j = 0; j < 4; j++) {
      float v1 = -INFINITY, v2 = -INFINITY;
      int i1 = -1, i2 = -1;
#pragma unroll
      for (int ni = 0; ni < 4; ni++)
        t2_add(acc[mi][ni][j], cbase + ni * 16, v1, i1, v2, i2);
      // reduce across the 16 column-lanes (same rows)
      for (int s = 1; s < 16; s <<= 1) {
        float ov1 = __shfl_xor(v1, s); int oi1 = __shfl_xor(i1, s);
        float ov2 = __shfl_xor(v2, s); int oi2 = __shfl_xor(i2, s);
        t2_add(ov1, oi1, v1, i1, v2, i2);
        t2_add(ov2, oi2, v1, i1, v2, i2);
      }
      if ((lane & 15) == 0) {
        int rl = wm * 128 + mi * 16 + ((lane >> 4) << 2) + j;
        buf[rl * 4 + wn] = make_float4(v1, v2, __int_as_float(i1), __int_as_float(i2));
      }
    }
  }
  __syncthreads();
  // combine wave-col pairs: (wn 0,1) -> half 0, (wn 2,3) -> half 1
  {
    const int row = tid >> 1, half = tid & 1;
    float4 a = buf[row * 4 + half * 2 + 0], b = buf[row * 4 + half * 2 + 1];
    float v1 = a.x, v2 = a.y;
    int i1 = __float_as_int(a.z), i2 = __float_as_int(a.w);
    t2_add(b.x, __float_as_int(b.z), v1, i1, v2, i2);
    t2_add(b.y, __float_as_int(b.w), v1, i1, v2, i2);
    pertile[(size_t)(n0 + row) * KTILES + kb * 2 + half] =
        make_float4(v1, v2, __int_as_float(i1), __int_as_float(i2));
  }
}

// ------- final argmax: global bf16 max, shortlist within DELTA, fp64 rescore
// Works on RAW hidden/emb: z-norm is a common factor (drops out of argmax);
// e-norm recomputed in fp64 per candidate. sim_rel = dot(z,e)/||e||.
#define DELTA 2e-3f
__global__ __launch_bounds__(256) void rescore_kernel(
    const float4* __restrict__ pertile, const float* __restrict__ hid,
    const float* __restrict__ emb, float* __restrict__ idx_f,
    int* __restrict__ idx_i) {
  const int n = blockIdx.x;
  const int t = threadIdx.x;
  __shared__ double sredd[2][4];
  __shared__ float sm[4];
  __shared__ int sl[128];
  __shared__ int scnt;

  float4 e4 = (t < 128) ? pertile[(size_t)n * KTILES + t]
                        : make_float4(-INFINITY, -INFINITY, 0.f, 0.f);
  float m = e4.x;
  for (int s = 32; s; s >>= 1) m = fmaxf(m, __shfl_xor(m, s));
  if ((t & 63) == 0) sm[t >> 6] = m;
  __syncthreads();
  if (t == 0) {
    sm[0] = fmaxf(fmaxf(sm[0], sm[1]), fmaxf(sm[2], sm[3]));
    scnt = 0;
  }
  __syncthreads();
  const float thr = sm[0] - DELTA;
  if (t < 128) {
    if (e4.x >= thr) { int p = atomicAdd(&scnt, 1); if (p < 128) sl[p] = __float_as_int(e4.z); }
    if (e4.y >= thr) { int p = atomicAdd(&scnt, 1); if (p < 128) sl[p] = __float_as_int(e4.w); }
  }
  __syncthreads();
  const int cnt = min(scnt, 128);

  // load raw z row (strided; n = b*1024 + hw)
  const int b = n >> 10, hw = n & 1023;
  const float* zbase = hid + (size_t)b * DIM * 1024 + hw;
  double zv[8];
#pragma unroll
  for (int j = 0; j < 8; j++) zv[j] = (double)zbase[(size_t)(t + 256 * j) * 1024];

  double bestv = -1e300;
  int besti = 0x7fffffff;
  for (int c = 0; c < cnt; c++) {
    const int k = sl[c];
    const float* erow = emb + (size_t)k * DIM;
    double dot = 0.0, ee = 0.0;
#pragma unroll
    for (int j = 0; j < 8; j++) {
      double ev = (double)erow[t + 256 * j];
      dot += zv[j] * ev;
      ee  += ev * ev;
    }
    for (int s = 32; s; s >>= 1) { dot += __shfl_down(dot, s); ee += __shfl_down(ee, s); }
    if ((t & 63) == 0) { sredd[0][t >> 6] = dot; sredd[1][t >> 6] = ee; }
    __syncthreads();
    if (t == 0) {
      double td = sredd[0][0] + sredd[0][1] + sredd[0][2] + sredd[0][3];
      double te = sredd[1][0] + sredd[1][1] + sredd[1][2] + sredd[1][3];
      double sim = td / sqrt(te);
      if (sim > bestv || (sim == bestv && k < besti)) { bestv = sim; besti = k; }
    }
    __syncthreads();
  }
  if (t == 0) { idx_f[n] = (float)besti; idx_i[n] = besti; }
}

// ------- gather emb[idx]/norm back to NCHW via LDS transpose ---------------
__global__ __launch_bounds__(256) void gather_kernel(
    const float* __restrict__ emb, const float* __restrict__ enorm,
    const int* __restrict__ idx, float* __restrict__ out) {
  const int bh = blockIdx.x;          // b*32 + h
  const int b = bh >> 5, h = bh & 31;
  const int n0 = bh * 32;
  const int c0 = blockIdx.y * 64;
  const int t = threadIdx.x;

  __shared__ int rows[32];
  __shared__ float nrm[32];
  __shared__ float tile[32][65];

  if (t < 32) {
    int r = idx[n0 + t];
    rows[t] = r;
    nrm[t] = enorm[r];
  }
  __syncthreads();
#pragma unroll
  for (int it = 0; it < 8; it++) {
    const int nl = it * 4 + (t >> 6);
    const int cl = t & 63;
    tile[nl][cl] = emb[(size_t)rows[nl] * DIM + c0 + cl] / nrm[nl];
  }
  __syncthreads();
#pragma unroll
  for (int jt = 0; jt < 8; jt++) {
    const int cl = jt * 8 + (t >> 5);
    const int w = t & 31;
    out[((size_t)(b * DIM + c0 + cl) << 10) + (h << 5) + w] = tile[w][cl];
  }
}

extern "C" void kernel_launch(void* const* d_in, const int* in_sizes, int n_in,
                              void* d_out, int out_size, void* d_ws, size_t ws_size,
                              hipStream_t stream) {
  const float* hidden = (const float*)d_in[0];  // (8,2048,32,32) fp32
  const float* emb    = (const float*)d_in[1];  // (16384,2048) fp32
  float* out = (float*)d_out;

  // workspace layout (~118 MB total)
  char* ws = (char*)d_ws;
  __hip_bfloat16* eh = (__hip_bfloat16*)ws; ws += (size_t)NK * DIM * 2;   // 67.1 MB
  __hip_bfloat16* zh = (__hip_bfloat16*)ws; ws += (size_t)NQ * DIM * 2;   // 33.6 MB
  float4* pertile = (float4*)ws;            ws += (size_t)NQ * KTILES * 16; // 16.8 MB
  float* enorm = (float*)ws;                ws += (size_t)NK * 4;         // 64 KB
  int* idxi = (int*)ws;                     ws += (size_t)NQ * 4;         // 32 KB

  norm_e_kernel<<<NK, 256, 0, stream>>>(emb, eh, enorm);
  norm_z_kernel<<<256, 256, 0, stream>>>(hidden, zh);
  gemm_top2<<<dim3(NQ / 256, NK / 256), 512, 0, stream>>>(zh, eh, pertile);
  rescore_kernel<<<NQ, 256, 0, stream>>>(pertile, hidden, emb, out + QUANT_ELEMS, idxi);
  gather_kernel<<<dim3(256, DIM / 64), 256, 0, stream>>>(emb, enorm, idxi, out);
}